// Round 6
// baseline (35.894 us; speedup 1.0000x reference)
//
#include <hip/hip_runtime.h>

#define BB 64
#define SS 512
#define DD 768
#define D4 192   // DD/4
#define BG 4     // b rows per tw block
#define KC 4     // k-chunks (partials) across blocks

typedef float v4f __attribute__((ext_vector_type(4)));

// Kernel A: part[kc][b][d] = sum_{k in chunk kc} topic[b][k] * W[k][d]
// grid (16, 12, 4), block 256. Each block: 4 b's, 64 d's (16 float4), 192 k's.
// 768 blocks (occupancy-proven) AND 4x W-reuse (37.7 MB L2 traffic).
__global__ void tw_part_kernel(const float* __restrict__ topic,
                               const float* __restrict__ W,
                               float* __restrict__ part) {
    __shared__ float t_s[BG][192];         // this block's k-chunk of 4 topic rows
    __shared__ float4 red[16][BG][16];     // 16 KB
    const int t  = threadIdx.x;
    const int b0 = blockIdx.x * BG;
    const int d4 = blockIdx.y * 16;        // tile start in float4 units
    const int k0 = blockIdx.z * 192;       // k-chunk start
    const int dl = t & 15;
    const int kg = t >> 4;                 // 0..15, sub-chain within chunk

    // stage the 4 topic sub-rows (4*192 = 768 floats, 3 per thread)
    for (int i = t; i < BG * 192; i += 256)
        t_s[i / 192][i % 192] = topic[(b0 + i / 192) * DD + k0 + (i % 192)];
    __syncthreads();

    const float4* __restrict__ W4 = (const float4*)W;  // [DD][D4]
    const int kk0 = kg * 12;
    float4 acc[BG];
#pragma unroll
    for (int bi = 0; bi < BG; ++bi) acc[bi] = make_float4(0.f, 0.f, 0.f, 0.f);

#pragma unroll
    for (int k = 0; k < 12; ++k) {
        const float4 w = W4[(size_t)(k0 + kk0 + k) * D4 + d4 + dl];
#pragma unroll
        for (int bi = 0; bi < BG; ++bi) {
            const float ts = t_s[bi][kk0 + k];
            acc[bi].x = fmaf(ts, w.x, acc[bi].x);
            acc[bi].y = fmaf(ts, w.y, acc[bi].y);
            acc[bi].z = fmaf(ts, w.z, acc[bi].z);
            acc[bi].w = fmaf(ts, w.w, acc[bi].w);
        }
    }
#pragma unroll
    for (int bi = 0; bi < BG; ++bi) red[kg][bi][dl] = acc[bi];
    __syncthreads();

    if (t < 64) {
        const int bi = t >> 4, d = t & 15;
        float4 s = red[0][bi][d];
#pragma unroll
        for (int j = 1; j < 16; ++j) {
            const float4 r = red[j][bi][d];
            s.x += r.x; s.y += r.y; s.z += r.z; s.w += r.w;
        }
        ((float4*)part)[((size_t)blockIdx.z * BB + b0 + bi) * D4 + d4 + d] = s;
    }
}

// Kernel B: scores[b][s] = sum_kc dot(part[kc][b], seq[b][s]) + bias
// One wave per score. seq nontemporal (streamed); partials L1-resident.
__global__ void score_kernel(const float* __restrict__ part,
                             const float* __restrict__ seq,
                             const float* __restrict__ bias,
                             float* __restrict__ scores) {
    const int gwid = (int)((blockIdx.x * blockDim.x + threadIdx.x) >> 6);
    const int lane = threadIdx.x & 63;
    const int b = gwid >> 9;      // / SS
    const int s = gwid & (SS - 1);

    const v4f* sp = (const v4f*)(seq + ((size_t)b * SS + s) * DD);
    const float4* pp = (const float4*)part;

    v4f x[3];
#pragma unroll
    for (int k = 0; k < 3; ++k) x[k] = __builtin_nontemporal_load(sp + lane + k * 64);

    float acc = 0.f;
#pragma unroll
    for (int kc = 0; kc < KC; ++kc) {
        const float4* tp = pp + ((size_t)kc * BB + b) * D4;
#pragma unroll
        for (int k = 0; k < 3; ++k) {
            const float4 tv = tp[lane + k * 64];
            acc = fmaf(x[k].x, tv.x, acc);
            acc = fmaf(x[k].y, tv.y, acc);
            acc = fmaf(x[k].z, tv.z, acc);
            acc = fmaf(x[k].w, tv.w, acc);
        }
    }
#pragma unroll
    for (int off = 32; off >= 1; off >>= 1) acc += __shfl_xor(acc, off);

    if (lane == 0) scores[gwid] = acc + bias[0];
}

// Kernel C: beta[b] = softmax(scores[b]) over S. One block of 512 per b.
__global__ void softmax_kernel(const float* __restrict__ scores,
                               float* __restrict__ beta) {
    __shared__ float red[8];
    __shared__ float s_m, s_sum;
    const int b   = blockIdx.x;
    const int tid = threadIdx.x;          // 0..511
    const int wid = tid >> 6, lane = tid & 63;

    const float v = scores[b * SS + tid];

    float m = v;
#pragma unroll
    for (int off = 32; off >= 1; off >>= 1) m = fmaxf(m, __shfl_xor(m, off));
    if (lane == 0) red[wid] = m;
    __syncthreads();
    if (tid == 0) {
        float mm = red[0];
#pragma unroll
        for (int i = 1; i < 8; ++i) mm = fmaxf(mm, red[i]);
        s_m = mm;
    }
    __syncthreads();

    const float e = __expf(v - s_m);
    float sum = e;
#pragma unroll
    for (int off = 32; off >= 1; off >>= 1) sum += __shfl_xor(sum, off);
    if (lane == 0) red[wid] = sum;
    __syncthreads();
    if (tid == 0) {
        float ss = 0.f;
#pragma unroll
        for (int i = 0; i < 8; ++i) ss += red[i];
        s_sum = ss;
    }
    __syncthreads();

    beta[b * SS + tid] = e / s_sum;
}

extern "C" void kernel_launch(void* const* d_in, const int* in_sizes, int n_in,
                              void* d_out, int out_size, void* d_ws, size_t ws_size,
                              hipStream_t stream) {
    const float* topic = (const float*)d_in[0];
    const float* seq   = (const float*)d_in[1];
    const float* W     = (const float*)d_in[2];
    const float* bias  = (const float*)d_in[3];
    float* out = (float*)d_out;

    float* part   = (float*)d_ws;                     // KC*BB*DD floats (786 KB)
    float* scores = part + (size_t)KC * BB * DD;      // BB*SS floats

    tw_part_kernel<<<dim3(BB / BG, 12, KC), 256, 0, stream>>>(topic, W, part);

    const int total_waves = BB * SS;              // one wave per score
    const int blocks = (total_waves * 64) / 256;  // 4 waves per block
    score_kernel<<<blocks, 256, 0, stream>>>(part, seq, bias, scores);

    softmax_kernel<<<BB, 512, 0, stream>>>(scores, out);
}

// Round 7
// 31.397 us; speedup vs baseline: 1.1432x; 1.1432x over previous
//
#include <hip/hip_runtime.h>

#define BB 64
#define SS 512
#define DD 768
#define D4 192   // DD/4
#define BG 4     // b rows per tw block

typedef float v4f __attribute__((ext_vector_type(4)));

// Kernel A v5: tW[b][d] = sum_k topic[b][k] * W[k][d]
// grid (16, 48), block 256. Each block: 4 b's, 16 d's (4 float4), full K=768.
// dl = t&3, kg = t>>2 -> 64 chains of 12 (fully unrolled, 12 loads in flight).
// 768 blocks (occupancy) AND 4x W-reuse (37.7 MB L2 traffic). Reduction:
// in-wave shfl_xor over the 16 local k-segments, then 1 KB LDS cross-wave.
__global__ void tw_kernel(const float* __restrict__ topic,
                          const float* __restrict__ W,
                          float* __restrict__ tW) {
    __shared__ float t_s[BG][DD];            // 12 KB
    __shared__ float4 red[4][BG][4];         // 1 KB
    const int t    = threadIdx.x;
    const int b0   = blockIdx.x * BG;
    const int d4   = blockIdx.y * 4;         // tile start in float4 units
    const int dl   = t & 3;
    const int kg   = t >> 2;                 // 0..63
    const int wv   = t >> 6;                 // 0..3
    const int lane = t & 63;

    // stage 4 contiguous topic rows (768 float4s, 3 per thread)
    {
        const float4* tp  = (const float4*)topic + (size_t)b0 * D4;
        float4*       ts4 = (float4*)t_s;
        ts4[t]       = tp[t];
        ts4[t + 256] = tp[t + 256];
        ts4[t + 512] = tp[t + 512];
    }
    __syncthreads();

    const float4* __restrict__ W4 = (const float4*)W;  // [DD][D4]
    const int k0 = kg * 12;
    float4 acc[BG];
#pragma unroll
    for (int bi = 0; bi < BG; ++bi) acc[bi] = make_float4(0.f, 0.f, 0.f, 0.f);

#pragma unroll
    for (int k = 0; k < 12; ++k) {
        const float4 w = W4[(size_t)(k0 + k) * D4 + d4 + dl];
#pragma unroll
        for (int bi = 0; bi < BG; ++bi) {
            const float ts = t_s[bi][k0 + k];
            acc[bi].x = fmaf(ts, w.x, acc[bi].x);
            acc[bi].y = fmaf(ts, w.y, acc[bi].y);
            acc[bi].z = fmaf(ts, w.z, acc[bi].z);
            acc[bi].w = fmaf(ts, w.w, acc[bi].w);
        }
    }

    // in-wave reduce across the 16 local k-segments (lane bits 2..5); dl kept
#pragma unroll
    for (int off = 4; off <= 32; off <<= 1) {
#pragma unroll
        for (int bi = 0; bi < BG; ++bi) {
            acc[bi].x += __shfl_xor(acc[bi].x, off);
            acc[bi].y += __shfl_xor(acc[bi].y, off);
            acc[bi].z += __shfl_xor(acc[bi].z, off);
            acc[bi].w += __shfl_xor(acc[bi].w, off);
        }
    }
    if (lane < 4) {                          // lane == dl here
#pragma unroll
        for (int bi = 0; bi < BG; ++bi) red[wv][bi][lane] = acc[bi];
    }
    __syncthreads();

    if (t < 16) {
        const int bi = t >> 2, d = t & 3;
        const float4 s0 = red[0][bi][d], s1 = red[1][bi][d];
        const float4 s2 = red[2][bi][d], s3 = red[3][bi][d];
        float4 s;
        s.x = (s0.x + s1.x) + (s2.x + s3.x);
        s.y = (s0.y + s1.y) + (s2.y + s3.y);
        s.z = (s0.z + s1.z) + (s2.z + s3.z);
        s.w = (s0.w + s1.w) + (s2.w + s3.w);
        ((float4*)tW)[(size_t)(b0 + bi) * D4 + d4 + d] = s;
    }
}

// Kernel B v4: scores[b][s] = dot(tW[b], seq[b][s]) + bias
// grid 2048, block 256: one block = one b x 16 s. tW row staged in LDS once,
// ds_reads hoisted out of the s-loop; per score only 3 nontemporal seq loads.
__global__ void score_kernel(const float* __restrict__ tW,
                             const float* __restrict__ seq,
                             const float* __restrict__ bias,
                             float* __restrict__ scores) {
    __shared__ float4 t_lds[D4];             // 3 KB
    const int t     = threadIdx.x;
    const int b     = blockIdx.x >> 5;
    const int chunk = blockIdx.x & 31;
    const int wv    = t >> 6, lane = t & 63;

    if (t < D4) t_lds[t] = ((const float4*)tW)[(size_t)b * D4 + t];
    __syncthreads();

    const float4 t0 = t_lds[lane];
    const float4 t1 = t_lds[lane + 64];
    const float4 t2 = t_lds[lane + 128];

    const int s0 = chunk * 16 + wv * 4;
#pragma unroll
    for (int i = 0; i < 4; ++i) {
        const int s = s0 + i;
        const v4f* sp = (const v4f*)(seq + ((size_t)b * SS + s) * DD);
        const v4f x0 = __builtin_nontemporal_load(sp + lane);
        const v4f x1 = __builtin_nontemporal_load(sp + lane + 64);
        const v4f x2 = __builtin_nontemporal_load(sp + lane + 128);

        float acc = 0.f;
        acc = fmaf(x0.x, t0.x, acc); acc = fmaf(x0.y, t0.y, acc);
        acc = fmaf(x0.z, t0.z, acc); acc = fmaf(x0.w, t0.w, acc);
        acc = fmaf(x1.x, t1.x, acc); acc = fmaf(x1.y, t1.y, acc);
        acc = fmaf(x1.z, t1.z, acc); acc = fmaf(x1.w, t1.w, acc);
        acc = fmaf(x2.x, t2.x, acc); acc = fmaf(x2.y, t2.y, acc);
        acc = fmaf(x2.z, t2.z, acc); acc = fmaf(x2.w, t2.w, acc);

#pragma unroll
        for (int off = 32; off >= 1; off >>= 1) acc += __shfl_xor(acc, off);

        if (lane == 0) scores[(size_t)b * SS + s] = acc + bias[0];
    }
}

// Kernel C: beta[b] = softmax(scores[b]) over S. One block of 512 per b.
__global__ void softmax_kernel(const float* __restrict__ scores,
                               float* __restrict__ beta) {
    __shared__ float red[8];
    __shared__ float s_m, s_sum;
    const int b   = blockIdx.x;
    const int tid = threadIdx.x;          // 0..511
    const int wid = tid >> 6, lane = tid & 63;

    const float v = scores[b * SS + tid];

    float m = v;
#pragma unroll
    for (int off = 32; off >= 1; off >>= 1) m = fmaxf(m, __shfl_xor(m, off));
    if (lane == 0) red[wid] = m;
    __syncthreads();
    if (tid == 0) {
        float mm = red[0];
#pragma unroll
        for (int i = 1; i < 8; ++i) mm = fmaxf(mm, red[i]);
        s_m = mm;
    }
    __syncthreads();

    const float e = __expf(v - s_m);
    float sum = e;
#pragma unroll
    for (int off = 32; off >= 1; off >>= 1) sum += __shfl_xor(sum, off);
    if (lane == 0) red[wid] = sum;
    __syncthreads();
    if (tid == 0) {
        float ss = 0.f;
#pragma unroll
        for (int i = 0; i < 8; ++i) ss += red[i];
        s_sum = ss;
    }
    __syncthreads();

    beta[b * SS + tid] = e / s_sum;
}

extern "C" void kernel_launch(void* const* d_in, const int* in_sizes, int n_in,
                              void* d_out, int out_size, void* d_ws, size_t ws_size,
                              hipStream_t stream) {
    const float* topic = (const float*)d_in[0];
    const float* seq   = (const float*)d_in[1];
    const float* W     = (const float*)d_in[2];
    const float* bias  = (const float*)d_in[3];
    float* out = (float*)d_out;

    float* tW     = (float*)d_ws;                 // BB*DD floats
    float* scores = tW + (size_t)BB * DD;         // BB*SS floats

    tw_kernel<<<dim3(BB / BG, DD / 16), 256, 0, stream>>>(topic, W, tW);

    score_kernel<<<BB * (SS / 16), 256, 0, stream>>>(tW, seq, bias, scores);

    softmax_kernel<<<BB, 512, 0, stream>>>(scores, out);
}